// Round 7
// baseline (2053.845 us; speedup 1.0000x reference)
//
#include <hip/hip_runtime.h>
#include <hip/hip_bf16.h>
#include <math.h>

typedef __attribute__((ext_vector_type(8))) short bf16x8;
typedef __attribute__((ext_vector_type(4))) float f32x4;

#define NBATCH   2048
#define MTILES   64          // 32 batches (352 rows) each; 64*352 = 22528 exact
#define NTILES   16          // 192 cols each (12 groups of 16)
#define NBLOCKS  (MTILES*NTILES)
#define LDS_TOTAL 139392     // epilogue stage: 6 regions * 176*33*4 B
#define ABUF0 0              // 22528 B  (352 rows x 32 k x bf16)
#define ABUF1 22528
#define BBUF0 45056          // 12288 B  (192 cols x 32 k x bf16)
#define BBUF1 57344
#define EPI_STRIDE 5808      // floats per region (176*33)

// A pre-packed bf16, MFMA-fragment-linear:
// [mtile 64][kstep 32][granule mf 0..21][lane 64][8]
__device__ unsigned short g_A[(size_t)MTILES*32*22*64*8];
// B packed bf16 fragment-linear: [g 192][kk 32][lane 64][8]
// g 0..31 = kW1, 32..63 = lW1, 64..127 = dW1a, 128..191 = dW1b
__device__ unsigned short g_wsB2[(size_t)192*32*64*8];
// partial sums, slot-major: [0..15] kinetic; 16 + j*11 + t local (j<16);
// 192 + j2*55 + p interaction (j2<64). col = batch.
__device__ float g_part[(size_t)3712*NBATCH];

static constexpr int II_[55] = {
    0,0,0,0,0,0,0,0,0,0, 1,1,1,1,1,1,1,1,1, 2,2,2,2,2,2,2,2,
    3,3,3,3,3,3,3, 4,4,4,4,4,4, 5,5,5,5,5, 6,6,6,6, 7,7,7, 8,8, 9};
static constexpr int JJ_[55] = {
    1,2,3,4,5,6,7,8,9,10, 2,3,4,5,6,7,8,9,10, 3,4,5,6,7,8,9,10,
    4,5,6,7,8,9,10, 5,6,7,8,9,10, 6,7,8,9,10, 7,8,9,10, 8,9,10, 9,10, 10};

__device__ __forceinline__ unsigned short f32_to_bf16u(float f) {
    unsigned u = __float_as_uint(f);
    u += 0x7fffu + ((u >> 16) & 1u);
    return (unsigned short)(u >> 16);
}

// 96 wave-pairs: pairIdx = ntile*6 + wn. <16 kinetic, <32 local, else interaction.
__device__ __forceinline__ int gmap(int pairIdx, int nf) {
    if (pairIdx < 16) return 2*pairIdx + nf;
    if (pairIdx < 32) return 32 + 2*(pairIdx-16) + nf;
    const int j2 = pairIdx - 32;
    return (nf ? 128 : 64) + j2;
}

__global__ void pack_A(const float* __restrict__ h) {
    const int t = blockIdx.x*256 + threadIdx.x;
    const int row = t >> 7, k8 = t & 127;
    const float* src = h + (size_t)row*1024 + k8*8;
    f32x4 a = *(const f32x4*)src;
    f32x4 b = *(const f32x4*)(src + 4);
    bf16x8 v;
    v[0]=(short)f32_to_bf16u(a[0]); v[1]=(short)f32_to_bf16u(a[1]);
    v[2]=(short)f32_to_bf16u(a[2]); v[3]=(short)f32_to_bf16u(a[3]);
    v[4]=(short)f32_to_bf16u(b[0]); v[5]=(short)f32_to_bf16u(b[1]);
    v[6]=(short)f32_to_bf16u(b[2]); v[7]=(short)f32_to_bf16u(b[3]);
    const int mtile = row / 352;
    const int rr = row - mtile*352;
    const int mf = rr >> 4, lo = rr & 15;
    const int kstep = k8 >> 2, h4 = k8 & 3;
    const size_t di = ((((size_t)mtile*32 + kstep)*22 + mf)*64 + (h4*16 + lo))*8;
    *(bf16x8*)(g_A + di) = v;
}

__global__ void pack_weights(const float* __restrict__ kW1,
                             const float* __restrict__ lW1,
                             const float* __restrict__ dW1) {
    const int t = blockIdx.x * 256 + threadIdx.x;
    const int lane = t & 63;
    const int kk   = (t >> 6) & 31;
    const int g    = t >> 11;
    const int col  = g * 16 + (lane & 15);
    const int k0   = kk * 32 + (lane >> 4) * 8;
    const float* src; int ncol, c;
    if (col < 512)       { src = kW1;                        ncol = 512;  c = col; }
    else if (col < 1024) { src = lW1;                        ncol = 512;  c = col - 512; }
    else if (col < 2048) { src = dW1;                        ncol = 1024; c = col - 1024; }
    else                 { src = dW1 + (size_t)1024 * 1024;  ncol = 1024; c = col - 2048; }
    bf16x8 v;
    #pragma unroll
    for (int j = 0; j < 8; ++j)
        v[j] = (short)f32_to_bf16u(src[(size_t)(k0 + j) * ncol + c]);
    *(bf16x8*)(g_wsB2 + (size_t)t * 8) = v;
}

// capture-free staging of one 1KB granule via global_load_lds
__device__ __forceinline__ void stage_granule(char* smem, int m, int n, int ln,
                                              int gi, int step, int aOff, int bOff) {
    const char* src; char* dst;
    if (gi < 22) {
        src = (const char*)g_A + ((((size_t)m*32 + step)*22 + gi)*64 + ln)*16;
        dst = smem + aOff + gi*1024;
    } else {
        const int j = gi - 22;
        const int G = gmap(n*6 + (j >> 1), j & 1);
        src = (const char*)g_wsB2 + (((size_t)G*32 + step)*64 + ln)*16;
        dst = smem + bOff + j*1024;
    }
    __builtin_amdgcn_global_load_lds(
        (const __attribute__((address_space(1))) unsigned int*)src,
        (__attribute__((address_space(3))) unsigned int*)dst, 16, 0, 0);
}

#define STAGE(step, aOff, bOff) do { \
    stage_granule(smem, m, n, ln, wv,      (step), (aOff), (bOff)); \
    stage_granule(smem, m, n, ln, wv + 12, (step), (aOff), (bOff)); \
    if (wv < 10) stage_granule(smem, m, n, ln, wv + 24, (step), (aOff), (bOff)); \
} while(0)

// epilogue as macro: acc arrays are never address-taken -> stay in VGPRs
#define EPILOGUE() do { \
  float* stg = (float*)smem + wn * EPI_STRIDE; \
  if (pairIdx < 32) { \
    const bool kin = pairIdx < 16; \
    const float* b1a = kin ? kb1 : lb1; \
    const float* w2a = kin ? kW2 : lW2; \
    const int c0 = (kin ? pairIdx : (pairIdx - 16)) * 32; \
    const float b1v0 = b1a[c0 + lo16],      w2v0 = w2a[c0 + lo16]; \
    const float b1v1 = b1a[c0 + 16 + lo16], w2v1 = w2a[c0 + 16 + lo16]; \
    _Pragma("unroll") \
    for (int mf = 0; mf < 11; ++mf) { \
      _Pragma("unroll") \
      for (int e = 0; e < 4; ++e) { \
        const int r = mf*16 + 4*hi4 + e; \
        stg[r*33 + lo16]      = fmaxf(accA[mf][e] + b1v0, 0.f) * w2v0; \
        stg[r*33 + 16 + lo16] = fmaxf(accB[mf][e] + b1v1, 0.f) * w2v1; \
      } } \
    asm volatile("s_waitcnt lgkmcnt(0)" ::: "memory"); \
    float rs0 = 0.f, rs1 = 0.f, rs2 = 0.f; \
    _Pragma("unroll") \
    for (int c = 0; c < 32; ++c) { \
      rs0 += stg[ln*33 + c]; \
      rs1 += stg[(ln + 64)*33 + c]; \
      if (ln < 48) rs2 += stg[(ln + 128)*33 + c]; \
    } \
    if (kin) { \
      asm volatile("s_waitcnt lgkmcnt(0)" ::: "memory"); \
      stg[ln] = rs0; stg[ln + 64] = rs1; \
      if (ln < 48) stg[ln + 128] = rs2; \
      asm volatile("s_waitcnt lgkmcnt(0)" ::: "memory"); \
      if (ln < 16) { \
        float s = 0.f; \
        _Pragma("unroll") \
        for (int t = 0; t < 11; ++t) s += stg[ln*11 + t]; \
        g_part[(size_t)pairIdx*NBATCH + bg0 + ln] = s; \
      } \
    } else { \
      const int base = 16 + (pairIdx - 16)*11; \
      { const int r = ln;       const int bb = (r*373)>>12; const int t = r - bb*11; \
        g_part[(size_t)(base + t)*NBATCH + bg0 + bb] = rs0; } \
      { const int r = ln + 64;  const int bb = (r*373)>>12; const int t = r - bb*11; \
        g_part[(size_t)(base + t)*NBATCH + bg0 + bb] = rs1; } \
      if (ln < 48) { \
        const int r = ln + 128; const int bb = (r*373)>>12; const int t = r - bb*11; \
        g_part[(size_t)(base + t)*NBATCH + bg0 + bb] = rs2; } \
    } \
  } else { \
    const int j2 = pairIdx - 32; \
    const float db1v = db1[j2*16 + lo16]; \
    const float dw2v = dW2[j2*16 + lo16]; \
    _Pragma("unroll") \
    for (int mf = 0; mf < 11; ++mf) { \
      _Pragma("unroll") \
      for (int e = 0; e < 4; ++e) { \
        const int r = mf*16 + 4*hi4 + e; \
        stg[r*33 + lo16]      = accA[mf][e]; \
        stg[r*33 + 16 + lo16] = accB[mf][e]; \
      } } \
    asm volatile("s_waitcnt lgkmcnt(0)" ::: "memory"); \
    _Pragma("unroll 1") \
    for (int it = 0; it < 4; ++it) { \
      const int bb = hi4 + 4*it; \
      float pi[11], pj[11]; \
      _Pragma("unroll") \
      for (int t = 0; t < 11; ++t) { \
        pi[t] = stg[(bb*11 + t)*33 + lo16] + db1v; \
        pj[t] = stg[(bb*11 + t)*33 + 16 + lo16]; \
      } \
      float aP[55]; \
      _Pragma("unroll") \
      for (int p = 0; p < 55; ++p) \
        aP[p] = fmaxf(pi[II_[p]] + pj[JJ_[p]], 0.f) * dw2v; \
      _Pragma("unroll") \
      for (int p = 0; p < 55; ++p) { \
        aP[p] += __shfl_xor(aP[p], 1); \
        aP[p] += __shfl_xor(aP[p], 2); \
        aP[p] += __shfl_xor(aP[p], 4); \
        aP[p] += __shfl_xor(aP[p], 8); \
      } \
      const int bg = bg0 + bb; \
      _Pragma("unroll") \
      for (int p = 0; p < 55; ++p) \
        if (lo16 == (p & 15)) \
          g_part[(size_t)(192 + j2*55 + p)*NBATCH + bg] = aP[p]; \
    } \
  } \
} while(0)

__launch_bounds__(768, 3)
__global__ void energy_mfma(
    const float* __restrict__ kb1, const float* __restrict__ kW2,
    const float* __restrict__ lb1, const float* __restrict__ lW2,
    const float* __restrict__ db1, const float* __restrict__ dW2)
{
    extern __shared__ char smem[];
    const int tid  = threadIdx.x;
    const int wv   = tid >> 6, ln = tid & 63;
    const int lo16 = ln & 15, hi4 = ln >> 4;
    const int wm   = wv / 6, wn = wv % 6;          // 2M x 6N waves
    const int bx   = blockIdx.x;
    const int x    = bx & 7, bi = bx >> 3;
    const int n    = 2*x + (bi >> 6);              // XCD x handles ntiles {2x, 2x+1}
    const int m    = bi & 63;
    const int pairIdx = n*6 + wn;
    const int bg0  = m*32 + wm*16;

    f32x4 accA[11], accB[11];
    #pragma unroll
    for (int mf = 0; mf < 11; ++mf) {
        accA[mf] = (f32x4){0.f,0.f,0.f,0.f};
        accB[mf] = (f32x4){0.f,0.f,0.f,0.f};
    }

    STAGE(0, ABUF0, BBUF0);
    asm volatile("s_waitcnt vmcnt(0)" ::: "memory");
    __syncthreads();

    int cur = 0;
    #pragma unroll 1
    for (int step = 0; step < 32; ++step) {
        if (step < 31) STAGE(step + 1, cur ? ABUF0 : ABUF1, cur ? BBUF0 : BBUF1);
        const char* Ab = smem + (cur ? ABUF1 : ABUF0) + (wm*11)*1024 + ln*16;
        const char* Bb = smem + (cur ? BBUF1 : BBUF0) + (wn*2)*1024 + ln*16;
        bf16x8 b0 = *(const bf16x8*)(Bb);
        bf16x8 b1 = *(const bf16x8*)(Bb + 1024);
        __builtin_amdgcn_s_setprio(1);
        #pragma unroll
        for (int mf = 0; mf < 11; ++mf) {
            bf16x8 af = *(const bf16x8*)(Ab + mf*1024);
            accA[mf] = __builtin_amdgcn_mfma_f32_16x16x32_bf16(af, b0, accA[mf], 0,0,0);
            accB[mf] = __builtin_amdgcn_mfma_f32_16x16x32_bf16(af, b1, accB[mf], 0,0,0);
        }
        __builtin_amdgcn_s_setprio(0);
        asm volatile("s_waitcnt vmcnt(0)" ::: "memory");
        __syncthreads();
        cur ^= 1;
    }

    // ---------------- epilogue (2 rounds x 6 waves; LDS region per wn) ----------------
    if (wm == 0) { EPILOGUE(); }
    __syncthreads();
    if (wm == 1) { EPILOGUE(); }
}

__global__ void finalize(
    const float* __restrict__ base_conf,
    const float* __restrict__ kb2, const float* __restrict__ lb2,
    const float* __restrict__ db2,
    const float* __restrict__ kwp, const float* __restrict__ lwp,
    const float* __restrict__ iwp, const float* __restrict__ tmpp,
    float* __restrict__ out)
{
    const int b = blockIdx.x*64 + threadIdx.x;
    if (b >= NBATCH) return;
    const float kw = kwp[0], lw = lwp[0], iw = iwp[0], temp = tmpp[0];

    float ks = 0.f;
    #pragma unroll
    for (int s = 0; s < 16; ++s) ks += g_part[(size_t)s*NBATCH + b];
    const float kinetic = -kw * (ks * (1.f/11.f) + kb2[0]);

    float ls = 0.f;
    #pragma unroll 1
    for (int t = 0; t < 11; ++t) {
        float v = lb2[0];
        #pragma unroll
        for (int j = 0; j < 16; ++j) v += g_part[(size_t)(16 + j*11 + t)*NBATCH + b];
        ls += fmaxf(v, 0.f);
    }
    const float local_e = lw * (ls * (1.f/11.f));

    float is = 0.f;
    #pragma unroll 1
    for (int p = 0; p < 55; ++p) {
        float v = db2[0];
        #pragma unroll
        for (int j = 0; j < 64; ++j) v += g_part[(size_t)(192 + j*55 + p)*NBATCH + b];
        is += fmaxf(v, 0.f) * (1.f / (float)(JJ_[p] - II_[p] + 1));
    }
    const float inter = iw * (is * (1.f/55.f));

    const float total = kinetic + local_e + inter;
    const float ec = 1.f / (1.f + expf(total / (fabsf(temp) + 0.1f)));
    out[0*NBATCH + b] = total;
    out[1*NBATCH + b] = kinetic;
    out[2*NBATCH + b] = local_e;
    out[3*NBATCH + b] = inter;
    out[4*NBATCH + b] = ec;
    out[5*NBATCH + b] = base_conf[b] * ec;
}

extern "C" void kernel_launch(void* const* d_in, const int* in_sizes, int n_in,
                              void* d_out, int out_size, void* d_ws, size_t ws_size,
                              hipStream_t stream) {
    const float* h_stack   = (const float*)d_in[0];
    const float* base_conf = (const float*)d_in[1];
    const float* kW1 = (const float*)d_in[2];
    const float* kb1 = (const float*)d_in[3];
    const float* kW2 = (const float*)d_in[4];
    const float* kb2 = (const float*)d_in[5];
    const float* lW1 = (const float*)d_in[6];
    const float* lb1 = (const float*)d_in[7];
    const float* lW2 = (const float*)d_in[8];
    const float* lb2 = (const float*)d_in[9];
    const float* dW1 = (const float*)d_in[10];
    const float* db1 = (const float*)d_in[11];
    const float* dW2 = (const float*)d_in[12];
    const float* db2 = (const float*)d_in[13];
    const float* kwp = (const float*)d_in[14];
    const float* lwp = (const float*)d_in[15];
    const float* iwp = (const float*)d_in[16];
    const float* tmpp= (const float*)d_in[17];
    float* out = (float*)d_out;

    hipLaunchKernelGGL(pack_A, dim3(11264), dim3(256), 0, stream, h_stack);
    hipLaunchKernelGGL(pack_weights, dim3(1536), dim3(256), 0, stream, kW1, lW1, dW1);

    hipFuncSetAttribute((const void*)energy_mfma,
                        hipFuncAttributeMaxDynamicSharedMemorySize, LDS_TOTAL);
    hipLaunchKernelGGL(energy_mfma, dim3(NBLOCKS), dim3(768), LDS_TOTAL, stream,
                       kb1, kW2, lb1, lW2, db1, dW2);

    hipLaunchKernelGGL(finalize, dim3(32), dim3(64), 0, stream,
                       base_conf, kb2, lb2, db2, kwp, lwp, iwp, tmpp, out);
}

// Round 8
// 1050.492 us; speedup vs baseline: 1.9551x; 1.9551x over previous
//
#include <hip/hip_runtime.h>
#include <hip/hip_bf16.h>
#include <math.h>

typedef __attribute__((ext_vector_type(8))) short bf16x8;
typedef __attribute__((ext_vector_type(4))) float f32x4;

#define NBATCH   2048
#define MTILES   64          // 32 batches (352 rows) each; 64*352 = 22528 exact
#define NTILES   24          // 128 cols each (4 pairs of 2x16)
#define NBLOCKS  (MTILES*NTILES)
#define EPI_STRIDE 5808      // floats per epilogue region (176*33)
#define LDS_TOTAL  92928     // 4 regions * 5808 * 4 B  (staging needs only 61440)
#define ABUF0 0              // 22528 B  (352 rows x 32 k bf16)
#define ABUF1 22528
#define BBUF0 45056          // 8192 B   (128 cols x 32 k bf16)
#define BBUF1 53248

// A pre-packed bf16, MFMA-fragment-linear:
// [mtile 64][kstep 32][granule mf 0..21][lane 64][8]
__device__ unsigned short g_A[(size_t)MTILES*32*22*64*8];
// B packed bf16 fragment-linear: [g 192][kk 32][lane 64][8]
// g 0..31 = kW1, 32..63 = lW1, 64..127 = dW1a, 128..191 = dW1b
__device__ unsigned short g_wsB2[(size_t)192*32*64*8];
// partial sums, slot-major: [0..15] kinetic; 16 + j*11 + t local (j<16);
// 192 + j2*55 + p interaction (j2<64). col = batch.
__device__ float g_part[(size_t)3712*NBATCH];

static constexpr int II_[55] = {
    0,0,0,0,0,0,0,0,0,0, 1,1,1,1,1,1,1,1,1, 2,2,2,2,2,2,2,2,
    3,3,3,3,3,3,3, 4,4,4,4,4,4, 5,5,5,5,5, 6,6,6,6, 7,7,7, 8,8, 9};
static constexpr int JJ_[55] = {
    1,2,3,4,5,6,7,8,9,10, 2,3,4,5,6,7,8,9,10, 3,4,5,6,7,8,9,10,
    4,5,6,7,8,9,10, 5,6,7,8,9,10, 6,7,8,9,10, 7,8,9,10, 8,9,10, 9,10, 10};

__device__ __forceinline__ unsigned short f32_to_bf16u(float f) {
    unsigned u = __float_as_uint(f);
    u += 0x7fffu + ((u >> 16) & 1u);
    return (unsigned short)(u >> 16);
}

// 96 pairs: pairIdx = ntile*4 + wnp. <16 kinetic, <32 local, else interaction.
__device__ __forceinline__ int gmap(int pairIdx, int nf) {
    if (pairIdx < 16) return 2*pairIdx + nf;
    if (pairIdx < 32) return 32 + 2*(pairIdx-16) + nf;
    const int j2 = pairIdx - 32;
    return (nf ? 128 : 64) + j2;
}

__global__ void pack_A(const float* __restrict__ h) {
    const int t = blockIdx.x*256 + threadIdx.x;
    const int row = t >> 7, k8 = t & 127;
    const float* src = h + (size_t)row*1024 + k8*8;
    f32x4 a = *(const f32x4*)src;
    f32x4 b = *(const f32x4*)(src + 4);
    bf16x8 v;
    v[0]=(short)f32_to_bf16u(a[0]); v[1]=(short)f32_to_bf16u(a[1]);
    v[2]=(short)f32_to_bf16u(a[2]); v[3]=(short)f32_to_bf16u(a[3]);
    v[4]=(short)f32_to_bf16u(b[0]); v[5]=(short)f32_to_bf16u(b[1]);
    v[6]=(short)f32_to_bf16u(b[2]); v[7]=(short)f32_to_bf16u(b[3]);
    const int mtile = row / 352;
    const int rr = row - mtile*352;
    const int mf = rr >> 4, lo = rr & 15;
    const int kstep = k8 >> 2, h4 = k8 & 3;
    const size_t di = ((((size_t)mtile*32 + kstep)*22 + mf)*64 + (h4*16 + lo))*8;
    *(bf16x8*)(g_A + di) = v;
}

__global__ void pack_weights(const float* __restrict__ kW1,
                             const float* __restrict__ lW1,
                             const float* __restrict__ dW1) {
    const int t = blockIdx.x * 256 + threadIdx.x;
    const int lane = t & 63;
    const int kk   = (t >> 6) & 31;
    const int g    = t >> 11;
    const int col  = g * 16 + (lane & 15);
    const int k0   = kk * 32 + (lane >> 4) * 8;
    const float* src; int ncol, c;
    if (col < 512)       { src = kW1;                        ncol = 512;  c = col; }
    else if (col < 1024) { src = lW1;                        ncol = 512;  c = col - 512; }
    else if (col < 2048) { src = dW1;                        ncol = 1024; c = col - 1024; }
    else                 { src = dW1 + (size_t)1024 * 1024;  ncol = 1024; c = col - 2048; }
    bf16x8 v;
    #pragma unroll
    for (int j = 0; j < 8; ++j)
        v[j] = (short)f32_to_bf16u(src[(size_t)(k0 + j) * ncol + c]);
    *(bf16x8*)(g_wsB2 + (size_t)t * 8) = v;
}

// capture-free staging of one 1KB granule via global_load_lds
__device__ __forceinline__ void stage_granule(char* smem, int m, int n, int ln,
                                              int gi, int step, int aOff, int bOff) {
    const char* src; char* dst;
    if (gi < 22) {
        src = (const char*)g_A + ((((size_t)m*32 + step)*22 + gi)*64 + ln)*16;
        dst = smem + aOff + gi*1024;
    } else {
        const int j = gi - 22;                  // 0..7
        const int G = gmap(n*4 + (j >> 1), j & 1);
        src = (const char*)g_wsB2 + (((size_t)G*32 + step)*64 + ln)*16;
        dst = smem + bOff + j*1024;
    }
    __builtin_amdgcn_global_load_lds(
        (const __attribute__((address_space(1))) unsigned int*)src,
        (__attribute__((address_space(3))) unsigned int*)dst, 16, 0, 0);
}

#define STAGE(step, aOff, bOff) do { \
    stage_granule(smem, m, n, ln, wv,      (step), (aOff), (bOff)); \
    stage_granule(smem, m, n, ln, wv + 8,  (step), (aOff), (bOff)); \
    stage_granule(smem, m, n, ln, wv + 16, (step), (aOff), (bOff)); \
    if (wv < 6) stage_granule(smem, m, n, ln, wv + 24, (step), (aOff), (bOff)); \
} while(0)

#define EPILOGUE() do { \
  float* stg = (float*)smem + wnp * EPI_STRIDE; \
  if (pairIdx < 32) { \
    const bool kin = pairIdx < 16; \
    const float* b1a = kin ? kb1 : lb1; \
    const float* w2a = kin ? kW2 : lW2; \
    const int c0 = (kin ? pairIdx : (pairIdx - 16)) * 32; \
    const float b1v0 = b1a[c0 + lo16],      w2v0 = w2a[c0 + lo16]; \
    const float b1v1 = b1a[c0 + 16 + lo16], w2v1 = w2a[c0 + 16 + lo16]; \
    _Pragma("unroll") \
    for (int mf = 0; mf < 11; ++mf) { \
      _Pragma("unroll") \
      for (int e = 0; e < 4; ++e) { \
        const int r = mf*16 + 4*hi4 + e; \
        stg[r*33 + lo16]      = fmaxf(accA[mf][e] + b1v0, 0.f) * w2v0; \
        stg[r*33 + 16 + lo16] = fmaxf(accB[mf][e] + b1v1, 0.f) * w2v1; \
      } } \
    asm volatile("s_waitcnt lgkmcnt(0)" ::: "memory"); \
    float rs0 = 0.f, rs1 = 0.f, rs2 = 0.f; \
    _Pragma("unroll") \
    for (int c = 0; c < 32; ++c) { \
      rs0 += stg[ln*33 + c]; \
      rs1 += stg[(ln + 64)*33 + c]; \
      if (ln < 48) rs2 += stg[(ln + 128)*33 + c]; \
    } \
    if (kin) { \
      asm volatile("s_waitcnt lgkmcnt(0)" ::: "memory"); \
      stg[ln] = rs0; stg[ln + 64] = rs1; \
      if (ln < 48) stg[ln + 128] = rs2; \
      asm volatile("s_waitcnt lgkmcnt(0)" ::: "memory"); \
      if (ln < 16) { \
        float s = 0.f; \
        _Pragma("unroll") \
        for (int t = 0; t < 11; ++t) s += stg[ln*11 + t]; \
        g_part[(size_t)pairIdx*NBATCH + bg0 + ln] = s; \
      } \
    } else { \
      const int base = 16 + (pairIdx - 16)*11; \
      { const int r = ln;       const int bb = (r*373)>>12; const int t = r - bb*11; \
        g_part[(size_t)(base + t)*NBATCH + bg0 + bb] = rs0; } \
      { const int r = ln + 64;  const int bb = (r*373)>>12; const int t = r - bb*11; \
        g_part[(size_t)(base + t)*NBATCH + bg0 + bb] = rs1; } \
      if (ln < 48) { \
        const int r = ln + 128; const int bb = (r*373)>>12; const int t = r - bb*11; \
        g_part[(size_t)(base + t)*NBATCH + bg0 + bb] = rs2; } \
    } \
  } else { \
    const int j2 = pairIdx - 32; \
    const float db1v = db1[j2*16 + lo16]; \
    const float dw2v = dW2[j2*16 + lo16]; \
    _Pragma("unroll") \
    for (int mf = 0; mf < 11; ++mf) { \
      _Pragma("unroll") \
      for (int e = 0; e < 4; ++e) { \
        const int r = mf*16 + 4*hi4 + e; \
        stg[r*33 + lo16]      = accA[mf][e]; \
        stg[r*33 + 16 + lo16] = accB[mf][e]; \
      } } \
    asm volatile("s_waitcnt lgkmcnt(0)" ::: "memory"); \
    _Pragma("unroll 1") \
    for (int it = 0; it < 4; ++it) { \
      const int bb = hi4 + 4*it; \
      float pi[11], pj[11]; \
      _Pragma("unroll") \
      for (int t = 0; t < 11; ++t) { \
        pi[t] = stg[(bb*11 + t)*33 + lo16] + db1v; \
        pj[t] = stg[(bb*11 + t)*33 + 16 + lo16]; \
      } \
      float aP[55]; \
      _Pragma("unroll") \
      for (int p = 0; p < 55; ++p) \
        aP[p] = fmaxf(pi[II_[p]] + pj[JJ_[p]], 0.f) * dw2v; \
      _Pragma("unroll") \
      for (int p = 0; p < 55; ++p) { \
        aP[p] += __shfl_xor(aP[p], 1); \
        aP[p] += __shfl_xor(aP[p], 2); \
        aP[p] += __shfl_xor(aP[p], 4); \
        aP[p] += __shfl_xor(aP[p], 8); \
      } \
      const int bg = bg0 + bb; \
      _Pragma("unroll") \
      for (int p = 0; p < 55; ++p) \
        if (lo16 == (p & 15)) \
          g_part[(size_t)(192 + j2*55 + p)*NBATCH + bg] = aP[p]; \
    } \
  } \
} while(0)

__launch_bounds__(512, 2)
__global__ void energy_mfma(
    const float* __restrict__ kb1, const float* __restrict__ kW2,
    const float* __restrict__ lb1, const float* __restrict__ lW2,
    const float* __restrict__ db1, const float* __restrict__ dW2)
{
    extern __shared__ char smem[];
    const int tid  = threadIdx.x;
    const int wv   = tid >> 6, ln = tid & 63;
    const int lo16 = ln & 15, hi4 = ln >> 4;
    const int wm   = wv >> 2, wnp = wv & 3;        // 2M x 4PAIR waves
    const int bx   = blockIdx.x;
    const int x    = bx & 7, bi = bx >> 3;         // x: XCD; bi 0..191
    const int n    = x*3 + (bi >> 6);              // XCD x owns ntiles 3x..3x+2
    const int m    = bi & 63;
    const int pairIdx = n*4 + wnp;
    const int bg0  = m*32 + wm*16;

    f32x4 accA[11], accB[11];
    #pragma unroll
    for (int mf = 0; mf < 11; ++mf) {
        accA[mf] = (f32x4){0.f,0.f,0.f,0.f};
        accB[mf] = (f32x4){0.f,0.f,0.f,0.f};
    }

    STAGE(0, ABUF0, BBUF0);
    asm volatile("s_waitcnt vmcnt(0)" ::: "memory");
    __syncthreads();

    int cur = 0;
    #pragma unroll 1
    for (int step = 0; step < 32; ++step) {
        if (step < 31) STAGE(step + 1, cur ? ABUF0 : ABUF1, cur ? BBUF0 : BBUF1);
        const char* Ab = smem + (cur ? ABUF1 : ABUF0) + (wm*11)*1024 + ln*16;
        const char* Bb = smem + (cur ? BBUF1 : BBUF0) + (wnp*2)*1024 + ln*16;
        bf16x8 b0 = *(const bf16x8*)(Bb);
        bf16x8 b1 = *(const bf16x8*)(Bb + 1024);
        __builtin_amdgcn_s_setprio(1);
        #pragma unroll
        for (int mf = 0; mf < 11; ++mf) {
            bf16x8 af = *(const bf16x8*)(Ab + mf*1024);
            accA[mf] = __builtin_amdgcn_mfma_f32_16x16x32_bf16(af, b0, accA[mf], 0,0,0);
            accB[mf] = __builtin_amdgcn_mfma_f32_16x16x32_bf16(af, b1, accB[mf], 0,0,0);
        }
        __builtin_amdgcn_s_setprio(0);
        asm volatile("s_waitcnt vmcnt(0)" ::: "memory");
        __syncthreads();
        cur ^= 1;
    }

    // epilogue: 2 rounds (wm); LDS region per wnp
    if (wm == 0) { EPILOGUE(); }
    __syncthreads();
    if (wm == 1) { EPILOGUE(); }
}

__global__ void finalize(
    const float* __restrict__ base_conf,
    const float* __restrict__ kb2, const float* __restrict__ lb2,
    const float* __restrict__ db2,
    const float* __restrict__ kwp, const float* __restrict__ lwp,
    const float* __restrict__ iwp, const float* __restrict__ tmpp,
    float* __restrict__ out)
{
    __shared__ float part[4][64][68];
    const int tid = threadIdx.x;
    const int ln = tid & 63, q = tid >> 6;
    const int b = blockIdx.x*64 + ln;

    { // kinetic quarter: slots 4q..4q+3
        float ks = 0.f;
        #pragma unroll
        for (int s = 0; s < 4; ++s) ks += g_part[(size_t)(4*q + s)*NBATCH + b];
        part[q][ln][0] = ks;
    }
    #pragma unroll 1
    for (int t = 0; t < 11; ++t) {  // local quarter: j in 4q..4q+3
        float v = 0.f;
        #pragma unroll
        for (int j = 0; j < 4; ++j)
            v += g_part[(size_t)(16 + (4*q + j)*11 + t)*NBATCH + b];
        part[q][ln][1 + t] = v;
    }
    #pragma unroll 1
    for (int p = 0; p < 55; ++p) {  // interaction quarter: j2 in 16q..16q+15
        float v = 0.f;
        #pragma unroll
        for (int j = 0; j < 16; ++j)
            v += g_part[(size_t)(192 + (16*q + j)*55 + p)*NBATCH + b];
        part[q][ln][12 + p] = v;
    }
    __syncthreads();

    if (q == 0) {
        const float kw = kwp[0], lw = lwp[0], iw = iwp[0], temp = tmpp[0];
        float ks = part[0][ln][0] + part[1][ln][0] + part[2][ln][0] + part[3][ln][0];
        const float kinetic = -kw * (ks * (1.f/11.f) + kb2[0]);

        float ls = 0.f;
        #pragma unroll
        for (int t = 0; t < 11; ++t) {
            float v = lb2[0] + part[0][ln][1+t] + part[1][ln][1+t]
                             + part[2][ln][1+t] + part[3][ln][1+t];
            ls += fmaxf(v, 0.f);
        }
        const float local_e = lw * (ls * (1.f/11.f));

        float is = 0.f;
        #pragma unroll
        for (int p = 0; p < 55; ++p) {
            float v = db2[0] + part[0][ln][12+p] + part[1][ln][12+p]
                             + part[2][ln][12+p] + part[3][ln][12+p];
            is += fmaxf(v, 0.f) * (1.f / (float)(JJ_[p] - II_[p] + 1));
        }
        const float inter = iw * (is * (1.f/55.f));

        const float total = kinetic + local_e + inter;
        const float ec = 1.f / (1.f + expf(total / (fabsf(temp) + 0.1f)));
        out[0*NBATCH + b] = total;
        out[1*NBATCH + b] = kinetic;
        out[2*NBATCH + b] = local_e;
        out[3*NBATCH + b] = inter;
        out[4*NBATCH + b] = ec;
        out[5*NBATCH + b] = base_conf[b] * ec;
    }
}

extern "C" void kernel_launch(void* const* d_in, const int* in_sizes, int n_in,
                              void* d_out, int out_size, void* d_ws, size_t ws_size,
                              hipStream_t stream) {
    const float* h_stack   = (const float*)d_in[0];
    const float* base_conf = (const float*)d_in[1];
    const float* kW1 = (const float*)d_in[2];
    const float* kb1 = (const float*)d_in[3];
    const float* kW2 = (const float*)d_in[4];
    const float* kb2 = (const float*)d_in[5];
    const float* lW1 = (const float*)d_in[6];
    const float* lb1 = (const float*)d_in[7];
    const float* lW2 = (const float*)d_in[8];
    const float* lb2 = (const float*)d_in[9];
    const float* dW1 = (const float*)d_in[10];
    const float* db1 = (const float*)d_in[11];
    const float* dW2 = (const float*)d_in[12];
    const float* db2 = (const float*)d_in[13];
    const float* kwp = (const float*)d_in[14];
    const float* lwp = (const float*)d_in[15];
    const float* iwp = (const float*)d_in[16];
    const float* tmpp= (const float*)d_in[17];
    float* out = (float*)d_out;

    hipLaunchKernelGGL(pack_A, dim3(11264), dim3(256), 0, stream, h_stack);
    hipLaunchKernelGGL(pack_weights, dim3(1536), dim3(256), 0, stream, kW1, lW1, dW1);

    hipFuncSetAttribute((const void*)energy_mfma,
                        hipFuncAttributeMaxDynamicSharedMemorySize, LDS_TOTAL);
    hipLaunchKernelGGL(energy_mfma, dim3(NBLOCKS), dim3(512), LDS_TOTAL, stream,
                       kb1, kW2, lb1, lW2, db1, dW2);

    hipLaunchKernelGGL(finalize, dim3(32), dim3(256), 0, stream,
                       base_conf, kb2, lb2, db2, kwp, lwp, iwp, tmpp, out);
}

// Round 9
// 400.479 us; speedup vs baseline: 5.1285x; 2.6231x over previous
//
#include <hip/hip_runtime.h>
#include <hip/hip_bf16.h>
#include <math.h>

typedef __attribute__((ext_vector_type(8))) short bf16x8;
typedef __attribute__((ext_vector_type(4))) float f32x4;

#define NBATCH   2048
#define MTILES   64          // 32 batches (352 rows) each; 64*352 = 22528 exact
#define NTILES   24          // 128 cols each (4 pairs of 2x16)
#define NBLOCKS  (MTILES*NTILES)
#define EPI_STRIDE 5808      // floats per epilogue region (176*33)
#define STG2_OFF   92928     // byte offset of stg2 area (4 regions * 896 floats)
#define LDS_TOTAL  107264    // 92928 + 4*896*4
#define ABUF0 0              // 22528 B  (352 rows x 32 k bf16)
#define ABUF1 22528
#define BBUF0 45056          // 8192 B   (128 cols x 32 k bf16)
#define BBUF1 53248

// A pre-packed bf16, MFMA-fragment-linear:
// [mtile 64][kstep 32][granule mf 0..21][lane 64][8]
__device__ unsigned short g_A[(size_t)MTILES*32*22*64*8];
// B packed bf16 fragment-linear: [g 192][kk 32][lane 64][8]
// g 0..31 = kW1, 32..63 = lW1, 64..127 = dW1a, 128..191 = dW1b
__device__ unsigned short g_wsB2[(size_t)192*32*64*8];
// kinetic/local partials, slot-major: [0..15] kinetic; 16 + j*11 + t local (j<16)
__device__ float g_partKL[(size_t)192*NBATCH];
// interaction partials: [j2 64][batch 2048][56] (full-line coalesced writes)
__device__ float g_partI[(size_t)64*NBATCH*56];

static constexpr int II_[55] = {
    0,0,0,0,0,0,0,0,0,0, 1,1,1,1,1,1,1,1,1, 2,2,2,2,2,2,2,2,
    3,3,3,3,3,3,3, 4,4,4,4,4,4, 5,5,5,5,5, 6,6,6,6, 7,7,7, 8,8, 9};
static constexpr int JJ_[55] = {
    1,2,3,4,5,6,7,8,9,10, 2,3,4,5,6,7,8,9,10, 3,4,5,6,7,8,9,10,
    4,5,6,7,8,9,10, 5,6,7,8,9,10, 6,7,8,9,10, 7,8,9,10, 8,9,10, 9,10, 10};

__device__ __forceinline__ unsigned short f32_to_bf16u(float f) {
    unsigned u = __float_as_uint(f);
    u += 0x7fffu + ((u >> 16) & 1u);
    return (unsigned short)(u >> 16);
}

// 96 pairs: pairIdx = n*4 + wnp. <16 kinetic, <32 local, else interaction.
__device__ __forceinline__ int gmap(int pairIdx, int nf) {
    if (pairIdx < 16) return 2*pairIdx + nf;
    if (pairIdx < 32) return 32 + 2*(pairIdx-16) + nf;
    const int j2 = pairIdx - 32;
    return (nf ? 128 : 64) + j2;
}

__global__ void pack_A(const float* __restrict__ h) {
    const int t = blockIdx.x*256 + threadIdx.x;
    const int row = t >> 7, k8 = t & 127;
    const float* src = h + (size_t)row*1024 + k8*8;
    f32x4 a = *(const f32x4*)src;
    f32x4 b = *(const f32x4*)(src + 4);
    bf16x8 v;
    v[0]=(short)f32_to_bf16u(a[0]); v[1]=(short)f32_to_bf16u(a[1]);
    v[2]=(short)f32_to_bf16u(a[2]); v[3]=(short)f32_to_bf16u(a[3]);
    v[4]=(short)f32_to_bf16u(b[0]); v[5]=(short)f32_to_bf16u(b[1]);
    v[6]=(short)f32_to_bf16u(b[2]); v[7]=(short)f32_to_bf16u(b[3]);
    const int mtile = row / 352;
    const int rr = row - mtile*352;
    const int mf = rr >> 4, lo = rr & 15;
    const int kstep = k8 >> 2, h4 = k8 & 3;
    const size_t di = ((((size_t)mtile*32 + kstep)*22 + mf)*64 + (h4*16 + lo))*8;
    *(bf16x8*)(g_A + di) = v;
}

__global__ void pack_weights(const float* __restrict__ kW1,
                             const float* __restrict__ lW1,
                             const float* __restrict__ dW1) {
    const int t = blockIdx.x * 256 + threadIdx.x;
    const int lane = t & 63;
    const int kk   = (t >> 6) & 31;
    const int g    = t >> 11;
    const int col  = g * 16 + (lane & 15);
    const int k0   = kk * 32 + (lane >> 4) * 8;
    const float* src; int ncol, c;
    if (col < 512)       { src = kW1;                        ncol = 512;  c = col; }
    else if (col < 1024) { src = lW1;                        ncol = 512;  c = col - 512; }
    else if (col < 2048) { src = dW1;                        ncol = 1024; c = col - 1024; }
    else                 { src = dW1 + (size_t)1024 * 1024;  ncol = 1024; c = col - 2048; }
    bf16x8 v;
    #pragma unroll
    for (int j = 0; j < 8; ++j)
        v[j] = (short)f32_to_bf16u(src[(size_t)(k0 + j) * ncol + c]);
    *(bf16x8*)(g_wsB2 + (size_t)t * 8) = v;
}

// capture-free staging of one 1KB granule via global_load_lds
__device__ __forceinline__ void stage_granule(char* smem, int m, int n, int ln,
                                              int gi, int step, int aOff, int bOff) {
    const char* src; char* dst;
    if (gi < 22) {
        src = (const char*)g_A + ((((size_t)m*32 + step)*22 + gi)*64 + ln)*16;
        dst = smem + aOff + gi*1024;
    } else {
        const int j = gi - 22;                  // 0..7
        const int G = gmap(n*4 + (j >> 1), j & 1);
        src = (const char*)g_wsB2 + (((size_t)G*32 + step)*64 + ln)*16;
        dst = smem + bOff + j*1024;
    }
    __builtin_amdgcn_global_load_lds(
        (const __attribute__((address_space(1))) unsigned int*)src,
        (__attribute__((address_space(3))) unsigned int*)dst, 16, 0, 0);
}

// uniform 4 loads per wave (waves 6,7 duplicate granules 28,29 — same src+dst)
#define STAGE(step, aOff, bOff) do { \
    stage_granule(smem, m, n, ln, wv,      (step), (aOff), (bOff)); \
    stage_granule(smem, m, n, ln, wv + 8,  (step), (aOff), (bOff)); \
    stage_granule(smem, m, n, ln, wv + 16, (step), (aOff), (bOff)); \
    stage_granule(smem, m, n, ln, (wv < 6) ? (wv + 24) : (wv + 22), (step), (aOff), (bOff)); \
} while(0)

#define EPILOGUE() do { \
  float* stg = (float*)smem + wnp * EPI_STRIDE; \
  if (pairIdx < 32) { \
    const bool kin = pairIdx < 16; \
    const float* b1a = kin ? kb1 : lb1; \
    const float* w2a = kin ? kW2 : lW2; \
    const int c0 = (kin ? pairIdx : (pairIdx - 16)) * 32; \
    const float b1v0 = b1a[c0 + lo16],      w2v0 = w2a[c0 + lo16]; \
    const float b1v1 = b1a[c0 + 16 + lo16], w2v1 = w2a[c0 + 16 + lo16]; \
    _Pragma("unroll") \
    for (int mf = 0; mf < 11; ++mf) { \
      _Pragma("unroll") \
      for (int e = 0; e < 4; ++e) { \
        const int r = mf*16 + 4*hi4 + e; \
        stg[r*33 + lo16]      = fmaxf(accA[mf][e] + b1v0, 0.f) * w2v0; \
        stg[r*33 + 16 + lo16] = fmaxf(accB[mf][e] + b1v1, 0.f) * w2v1; \
      } } \
    asm volatile("s_waitcnt lgkmcnt(0)" ::: "memory"); \
    float rs0 = 0.f, rs1 = 0.f, rs2 = 0.f; \
    _Pragma("unroll") \
    for (int c = 0; c < 32; ++c) { \
      rs0 += stg[ln*33 + c]; \
      rs1 += stg[(ln + 64)*33 + c]; \
      if (ln < 48) rs2 += stg[(ln + 128)*33 + c]; \
    } \
    if (kin) { \
      asm volatile("s_waitcnt lgkmcnt(0)" ::: "memory"); \
      stg[ln] = rs0; stg[ln + 64] = rs1; \
      if (ln < 48) stg[ln + 128] = rs2; \
      asm volatile("s_waitcnt lgkmcnt(0)" ::: "memory"); \
      if (ln < 16) { \
        float s = 0.f; \
        _Pragma("unroll") \
        for (int t = 0; t < 11; ++t) s += stg[ln*11 + t]; \
        g_partKL[(size_t)pairIdx*NBATCH + bg0 + ln] = s; \
      } \
    } else { \
      const int base = 16 + (pairIdx - 16)*11; \
      { const int r = ln;       const int bb = (r*373)>>12; const int t = r - bb*11; \
        g_partKL[(size_t)(base + t)*NBATCH + bg0 + bb] = rs0; } \
      { const int r = ln + 64;  const int bb = (r*373)>>12; const int t = r - bb*11; \
        g_partKL[(size_t)(base + t)*NBATCH + bg0 + bb] = rs1; } \
      if (ln < 48) { \
        const int r = ln + 128; const int bb = (r*373)>>12; const int t = r - bb*11; \
        g_partKL[(size_t)(base + t)*NBATCH + bg0 + bb] = rs2; } \
    } \
  } else { \
    const int j2 = pairIdx - 32; \
    float* stg2 = (float*)(smem + STG2_OFF) + wnp * 896; \
    const float db1v = db1[j2*16 + lo16]; \
    const float dw2v = dW2[j2*16 + lo16]; \
    _Pragma("unroll") \
    for (int mf = 0; mf < 11; ++mf) { \
      _Pragma("unroll") \
      for (int e = 0; e < 4; ++e) { \
        const int r = mf*16 + 4*hi4 + e; \
        stg[r*33 + lo16]      = accA[mf][e]; \
        stg[r*33 + 16 + lo16] = accB[mf][e]; \
      } } \
    asm volatile("s_waitcnt lgkmcnt(0)" ::: "memory"); \
    _Pragma("unroll 1") \
    for (int it = 0; it < 4; ++it) { \
      const int bb = hi4 + 4*it; \
      float pi[11], pj[11]; \
      _Pragma("unroll") \
      for (int t = 0; t < 11; ++t) { \
        pi[t] = stg[(bb*11 + t)*33 + lo16] + db1v; \
        pj[t] = stg[(bb*11 + t)*33 + 16 + lo16]; \
      } \
      { /* pass 0: p 0..27 */ \
        float aP[28]; \
        _Pragma("unroll") \
        for (int p = 0; p < 28; ++p) \
          aP[p] = fmaxf(pi[II_[p]] + pj[JJ_[p]], 0.f) * dw2v; \
        _Pragma("unroll") \
        for (int p = 0; p < 28; ++p) { \
          aP[p] += __shfl_xor(aP[p], 1); \
          aP[p] += __shfl_xor(aP[p], 2); \
          aP[p] += __shfl_xor(aP[p], 4); \
          aP[p] += __shfl_xor(aP[p], 8); \
        } \
        _Pragma("unroll") \
        for (int p = 0; p < 28; ++p) \
          if (lo16 == (p & 15)) stg2[bb*56 + p] = aP[p]; \
      } \
      { /* pass 1: p 28..54 */ \
        float aP[27]; \
        _Pragma("unroll") \
        for (int p = 0; p < 27; ++p) \
          aP[p] = fmaxf(pi[II_[p+28]] + pj[JJ_[p+28]], 0.f) * dw2v; \
        _Pragma("unroll") \
        for (int p = 0; p < 27; ++p) { \
          aP[p] += __shfl_xor(aP[p], 1); \
          aP[p] += __shfl_xor(aP[p], 2); \
          aP[p] += __shfl_xor(aP[p], 4); \
          aP[p] += __shfl_xor(aP[p], 8); \
        } \
        _Pragma("unroll") \
        for (int p = 0; p < 27; ++p) \
          if (lo16 == ((p+28) & 15)) stg2[bb*56 + (p+28)] = aP[p]; \
      } \
    } \
    asm volatile("s_waitcnt lgkmcnt(0)" ::: "memory"); \
    { /* coalesced copy stg2 -> g_partI[j2][bg0..bg0+15][56] */ \
      float* gdst = g_partI + ((size_t)j2*NBATCH + bg0) * 56; \
      _Pragma("unroll") \
      for (int i = 0; i < 14; ++i) gdst[ln + 64*i] = stg2[ln + 64*i]; \
    } \
  } \
} while(0)

__launch_bounds__(512, 1)
__global__ void energy_mfma(
    const float* __restrict__ kb1, const float* __restrict__ kW2,
    const float* __restrict__ lb1, const float* __restrict__ lW2,
    const float* __restrict__ db1, const float* __restrict__ dW2)
{
    extern __shared__ char smem[];
    const int tid  = threadIdx.x;
    const int wv   = tid >> 6, ln = tid & 63;
    const int lo16 = ln & 15, hi4 = ln >> 4;
    const int wm   = wv >> 2, wnp = wv & 3;        // 2M x 4PAIR waves
    const int bx   = blockIdx.x;
    const int n    = bx >> 6;                      // 0..23
    const int m    = bx & 63;                      // 0..63
    const int pairIdx = n*4 + wnp;
    const int bg0  = m*32 + wm*16;

    f32x4 accA[11], accB[11];
    #pragma unroll
    for (int mf = 0; mf < 11; ++mf) {
        accA[mf] = (f32x4){0.f,0.f,0.f,0.f};
        accB[mf] = (f32x4){0.f,0.f,0.f,0.f};
    }

    STAGE(0, ABUF0, BBUF0);

    int cur = 0;
    #pragma unroll 1
    for (int step = 0; step < 32; ++step) {
        if (step < 31) {
            STAGE(step + 1, cur ? ABUF0 : ABUF1, cur ? BBUF0 : BBUF1);
            asm volatile("s_waitcnt vmcnt(4)" ::: "memory");
        } else {
            asm volatile("s_waitcnt vmcnt(0)" ::: "memory");
        }
        __builtin_amdgcn_s_barrier();              // buf[cur] fully staged for all waves
        const char* Ab = smem + (cur ? ABUF1 : ABUF0) + (wm*11)*1024 + ln*16;
        const char* Bb = smem + (cur ? BBUF1 : BBUF0) + (wnp*2)*1024 + ln*16;
        bf16x8 b0 = *(const bf16x8*)(Bb);
        bf16x8 b1 = *(const bf16x8*)(Bb + 1024);
        __builtin_amdgcn_s_setprio(1);
        #pragma unroll
        for (int mf = 0; mf < 11; ++mf) {
            bf16x8 af = *(const bf16x8*)(Ab + mf*1024);
            accA[mf] = __builtin_amdgcn_mfma_f32_16x16x32_bf16(af, b0, accA[mf], 0,0,0);
            accB[mf] = __builtin_amdgcn_mfma_f32_16x16x32_bf16(af, b1, accB[mf], 0,0,0);
        }
        __builtin_amdgcn_s_setprio(0);
        asm volatile("" ::: "memory");             // fence: reads stay before barrier
        __builtin_amdgcn_s_barrier();              // all reads of buf[cur] done before re-stage
        cur ^= 1;
    }

    // epilogue: 2 rounds (wm); LDS regions per wnp (overlap dead staging buffers)
    if (wm == 0) { EPILOGUE(); }
    __syncthreads();
    if (wm == 1) { EPILOGUE(); }
}

__global__ void finalize(
    const float* __restrict__ base_conf,
    const float* __restrict__ kb2, const float* __restrict__ lb2,
    const float* __restrict__ db2,
    const float* __restrict__ kwp, const float* __restrict__ lwp,
    const float* __restrict__ iwp, const float* __restrict__ tmpp,
    float* __restrict__ out)
{
    const int wv = threadIdx.x >> 6, ln = threadIdx.x & 63;
    const int b0 = (blockIdx.x*4 + wv)*4;          // 4 batches per wave
    const float kw = kwp[0], lw = lwp[0], iw = iwp[0], temp = tmpp[0];
    const float kb2v = kb2[0], lb2v = lb2[0], db2v = db2[0];

    #pragma unroll 1
    for (int bi = 0; bi < 4; ++bi) {
        const int b = b0 + bi;

        // ---- interaction: lane = j2, coalesced 16B chunks, full-wave reduce ----
        float is = 0.f;
        const float* ibase = g_partI + ((size_t)ln*NBATCH + b)*56;
        #pragma unroll
        for (int c = 0; c < 14; ++c) {
            f32x4 v = *(const f32x4*)(ibase + c*4);
            #pragma unroll
            for (int msk = 1; msk <= 32; msk <<= 1) {
                v[0] += __shfl_xor(v[0], msk);
                v[1] += __shfl_xor(v[1], msk);
                v[2] += __shfl_xor(v[2], msk);
                v[3] += __shfl_xor(v[3], msk);
            }
            #pragma unroll
            for (int k = 0; k < 4; ++k) {
                const int p = c*4 + k;
                if (p < 55)
                    is += fmaxf(v[k] + db2v, 0.f) *
                          (1.f / (float)(JJ_[p] - II_[p] + 1));
            }
        }

        // ---- kinetic: slots 0..15 ----
        float kv = (ln < 16) ? g_partKL[(size_t)ln*NBATCH + b] : 0.f;
        #pragma unroll
        for (int msk = 1; msk <= 32; msk <<= 1) kv += __shfl_xor(kv, msk);
        const float kinetic = -kw * (kv * (1.f/11.f) + kb2v);

        // ---- local: lane t<11 sums 16 j's, then gather ----
        float lv = 0.f;
        if (ln < 11) {
            #pragma unroll
            for (int j = 0; j < 16; ++j)
                lv += g_partKL[(size_t)(16 + j*11 + ln)*NBATCH + b];
        }
        float ls = 0.f;
        #pragma unroll
        for (int t = 0; t < 11; ++t)
            ls += fmaxf(__shfl(lv, t) + lb2v, 0.f);
        const float local_e = lw * (ls * (1.f/11.f));

        const float inter = iw * (is * (1.f/55.f));
        const float total = kinetic + local_e + inter;
        const float ec = 1.f / (1.f + expf(total / (fabsf(temp) + 0.1f)));
        if (ln == 0) {
            out[0*NBATCH + b] = total;
            out[1*NBATCH + b] = kinetic;
            out[2*NBATCH + b] = local_e;
            out[3*NBATCH + b] = inter;
            out[4*NBATCH + b] = ec;
            out[5*NBATCH + b] = base_conf[b] * ec;
        }
    }
}

extern "C" void kernel_launch(void* const* d_in, const int* in_sizes, int n_in,
                              void* d_out, int out_size, void* d_ws, size_t ws_size,
                              hipStream_t stream) {
    const float* h_stack   = (const float*)d_in[0];
    const float* base_conf = (const float*)d_in[1];
    const float* kW1 = (const float*)d_in[2];
    const float* kb1 = (const float*)d_in[3];
    const float* kW2 = (const float*)d_in[4];
    const float* kb2 = (const float*)d_in[5];
    const float* lW1 = (const float*)d_in[6];
    const float* lb1 = (const float*)d_in[7];
    const float* lW2 = (const float*)d_in[8];
    const float* lb2 = (const float*)d_in[9];
    const float* dW1 = (const float*)d_in[10];
    const float* db1 = (const float*)d_in[11];
    const float* dW2 = (const float*)d_in[12];
    const float* db2 = (const float*)d_in[13];
    const float* kwp = (const float*)d_in[14];
    const float* lwp = (const float*)d_in[15];
    const float* iwp = (const float*)d_in[16];
    const float* tmpp= (const float*)d_in[17];
    float* out = (float*)d_out;

    hipLaunchKernelGGL(pack_A, dim3(11264), dim3(256), 0, stream, h_stack);
    hipLaunchKernelGGL(pack_weights, dim3(1536), dim3(256), 0, stream, kW1, lW1, dW1);

    hipFuncSetAttribute((const void*)energy_mfma,
                        hipFuncAttributeMaxDynamicSharedMemorySize, LDS_TOTAL);
    hipLaunchKernelGGL(energy_mfma, dim3(NBLOCKS), dim3(512), LDS_TOTAL, stream,
                       kb1, kW2, lb1, lW2, db1, dW2);

    hipLaunchKernelGGL(finalize, dim3(128), dim3(256), 0, stream,
                       base_conf, kb2, lb2, db2, kwp, lwp, iwp, tmpp, out);
}

// Round 10
// 392.771 us; speedup vs baseline: 5.2291x; 1.0196x over previous
//
#include <hip/hip_runtime.h>
#include <hip/hip_bf16.h>
#include <math.h>

typedef __attribute__((ext_vector_type(8))) short bf16x8;
typedef __attribute__((ext_vector_type(4))) float f32x4;

#define NBATCH   2048
#define MTILES   64          // 32 batches (352 rows) each; 64*352 = 22528 exact
#define NTILES   24          // 128 cols each (4 pairs of 2x16)
#define NBLOCKS  (MTILES*NTILES)
#define EPI_STRIDE 5808      // floats per epilogue region (176*33)
#define STG2_OFF   92928     // byte offset of stg2 area (4 regions * 896 floats)
#define ABYTES   22528       // 352 rows x 32 k bf16
#define BUFSZ    30720       // ABYTES + 8192 B of B
#define LDS_TOTAL (4*BUFSZ)  // 122880: quad-buffered staging; epilogue aliases it

// A pre-packed bf16, MFMA-fragment-linear:
// [mtile 64][kstep 32][granule mf 0..21][lane 64][8]
__device__ unsigned short g_A[(size_t)MTILES*32*22*64*8];
// B packed bf16 fragment-linear: [g 192][kk 32][lane 64][8]
// g 0..31 = kW1, 32..63 = lW1, 64..127 = dW1a, 128..191 = dW1b
__device__ unsigned short g_wsB2[(size_t)192*32*64*8];
// kinetic/local partials, slot-major: [0..15] kinetic; 16 + j*11 + t local (j<16)
__device__ float g_partKL[(size_t)192*NBATCH];
// interaction partials: [j2 64][batch 2048][56] (full-line coalesced writes)
__device__ float g_partI[(size_t)64*NBATCH*56];

static constexpr int II_[55] = {
    0,0,0,0,0,0,0,0,0,0, 1,1,1,1,1,1,1,1,1, 2,2,2,2,2,2,2,2,
    3,3,3,3,3,3,3, 4,4,4,4,4,4, 5,5,5,5,5, 6,6,6,6, 7,7,7, 8,8, 9};
static constexpr int JJ_[55] = {
    1,2,3,4,5,6,7,8,9,10, 2,3,4,5,6,7,8,9,10, 3,4,5,6,7,8,9,10,
    4,5,6,7,8,9,10, 5,6,7,8,9,10, 6,7,8,9,10, 7,8,9,10, 8,9,10, 9,10, 10};

__device__ __forceinline__ unsigned short f32_to_bf16u(float f) {
    unsigned u = __float_as_uint(f);
    u += 0x7fffu + ((u >> 16) & 1u);
    return (unsigned short)(u >> 16);
}

// 96 pairs: pairIdx = n*4 + wnp. <16 kinetic, <32 local, else interaction.
__device__ __forceinline__ int gmap(int pairIdx, int nf) {
    if (pairIdx < 16) return 2*pairIdx + nf;
    if (pairIdx < 32) return 32 + 2*(pairIdx-16) + nf;
    const int j2 = pairIdx - 32;
    return (nf ? 128 : 64) + j2;
}

__global__ void pack_A(const float* __restrict__ h) {
    const int t = blockIdx.x*256 + threadIdx.x;
    const int row = t >> 7, k8 = t & 127;
    const float* src = h + (size_t)row*1024 + k8*8;
    f32x4 a = *(const f32x4*)src;
    f32x4 b = *(const f32x4*)(src + 4);
    bf16x8 v;
    v[0]=(short)f32_to_bf16u(a[0]); v[1]=(short)f32_to_bf16u(a[1]);
    v[2]=(short)f32_to_bf16u(a[2]); v[3]=(short)f32_to_bf16u(a[3]);
    v[4]=(short)f32_to_bf16u(b[0]); v[5]=(short)f32_to_bf16u(b[1]);
    v[6]=(short)f32_to_bf16u(b[2]); v[7]=(short)f32_to_bf16u(b[3]);
    const int mtile = row / 352;
    const int rr = row - mtile*352;
    const int mf = rr >> 4, lo = rr & 15;
    const int kstep = k8 >> 2, h4 = k8 & 3;
    const size_t di = ((((size_t)mtile*32 + kstep)*22 + mf)*64 + (h4*16 + lo))*8;
    *(bf16x8*)(g_A + di) = v;
}

__global__ void pack_weights(const float* __restrict__ kW1,
                             const float* __restrict__ lW1,
                             const float* __restrict__ dW1) {
    const int t = blockIdx.x * 256 + threadIdx.x;
    const int lane = t & 63;
    const int kk   = (t >> 6) & 31;
    const int g    = t >> 11;
    const int col  = g * 16 + (lane & 15);
    const int k0   = kk * 32 + (lane >> 4) * 8;
    const float* src; int ncol, c;
    if (col < 512)       { src = kW1;                        ncol = 512;  c = col; }
    else if (col < 1024) { src = lW1;                        ncol = 512;  c = col - 512; }
    else if (col < 2048) { src = dW1;                        ncol = 1024; c = col - 1024; }
    else                 { src = dW1 + (size_t)1024 * 1024;  ncol = 1024; c = col - 2048; }
    bf16x8 v;
    #pragma unroll
    for (int j = 0; j < 8; ++j)
        v[j] = (short)f32_to_bf16u(src[(size_t)(k0 + j) * ncol + c]);
    *(bf16x8*)(g_wsB2 + (size_t)t * 8) = v;
}

// capture-free staging of one 1KB granule via global_load_lds
__device__ __forceinline__ void stage_granule(char* smem, int m, int n, int ln,
                                              int gi, int step, int aOff, int bOff) {
    const char* src; char* dst;
    if (gi < 22) {
        src = (const char*)g_A + ((((size_t)m*32 + step)*22 + gi)*64 + ln)*16;
        dst = smem + aOff + gi*1024;
    } else {
        const int j = gi - 22;                  // 0..7
        const int G = gmap(n*4 + (j >> 1), j & 1);
        src = (const char*)g_wsB2 + (((size_t)G*32 + step)*64 + ln)*16;
        dst = smem + bOff + j*1024;
    }
    __builtin_amdgcn_global_load_lds(
        (const __attribute__((address_space(1))) unsigned int*)src,
        (__attribute__((address_space(3))) unsigned int*)dst, 16, 0, 0);
}

// uniform 4 loads per wave (waves 6,7 duplicate granules 28,29 — same src+dst)
#define STAGE(step, bufbase) do { \
    stage_granule(smem, m, n, ln, wv,      (step), (bufbase), (bufbase) + ABYTES); \
    stage_granule(smem, m, n, ln, wv + 8,  (step), (bufbase), (bufbase) + ABYTES); \
    stage_granule(smem, m, n, ln, wv + 16, (step), (bufbase), (bufbase) + ABYTES); \
    stage_granule(smem, m, n, ln, (wv < 6) ? (wv + 24) : (wv + 22), (step), (bufbase), (bufbase) + ABYTES); \
} while(0)

#define MFMA_PHASE(bufbase) do { \
    const char* Ab = smem + (bufbase) + (wm*11)*1024 + ln*16; \
    const char* Bb = smem + (bufbase) + ABYTES + (wnp*2)*1024 + ln*16; \
    bf16x8 b0 = *(const bf16x8*)(Bb); \
    bf16x8 b1 = *(const bf16x8*)(Bb + 1024); \
    __builtin_amdgcn_s_setprio(1); \
    _Pragma("unroll") \
    for (int mf = 0; mf < 11; ++mf) { \
        bf16x8 af = *(const bf16x8*)(Ab + mf*1024); \
        accA[mf] = __builtin_amdgcn_mfma_f32_16x16x32_bf16(af, b0, accA[mf], 0,0,0); \
        accB[mf] = __builtin_amdgcn_mfma_f32_16x16x32_bf16(af, b1, accB[mf], 0,0,0); \
    } \
    __builtin_amdgcn_s_setprio(0); \
} while(0)

#define EPILOGUE() do { \
  float* stg = (float*)smem + wnp * EPI_STRIDE; \
  if (pairIdx < 32) { \
    const bool kin = pairIdx < 16; \
    const float* b1a = kin ? kb1 : lb1; \
    const float* w2a = kin ? kW2 : lW2; \
    const int c0 = (kin ? pairIdx : (pairIdx - 16)) * 32; \
    const float b1v0 = b1a[c0 + lo16],      w2v0 = w2a[c0 + lo16]; \
    const float b1v1 = b1a[c0 + 16 + lo16], w2v1 = w2a[c0 + 16 + lo16]; \
    _Pragma("unroll") \
    for (int mf = 0; mf < 11; ++mf) { \
      _Pragma("unroll") \
      for (int e = 0; e < 4; ++e) { \
        const int r = mf*16 + 4*hi4 + e; \
        stg[r*33 + lo16]      = fmaxf(accA[mf][e] + b1v0, 0.f) * w2v0; \
        stg[r*33 + 16 + lo16] = fmaxf(accB[mf][e] + b1v1, 0.f) * w2v1; \
      } } \
    asm volatile("s_waitcnt lgkmcnt(0)" ::: "memory"); \
    float rs0 = 0.f, rs1 = 0.f, rs2 = 0.f; \
    _Pragma("unroll") \
    for (int c = 0; c < 32; ++c) { \
      rs0 += stg[ln*33 + c]; \
      rs1 += stg[(ln + 64)*33 + c]; \
      if (ln < 48) rs2 += stg[(ln + 128)*33 + c]; \
    } \
    if (kin) { \
      asm volatile("s_waitcnt lgkmcnt(0)" ::: "memory"); \
      stg[ln] = rs0; stg[ln + 64] = rs1; \
      if (ln < 48) stg[ln + 128] = rs2; \
      asm volatile("s_waitcnt lgkmcnt(0)" ::: "memory"); \
      if (ln < 16) { \
        float s = 0.f; \
        _Pragma("unroll") \
        for (int t = 0; t < 11; ++t) s += stg[ln*11 + t]; \
        g_partKL[(size_t)pairIdx*NBATCH + bg0 + ln] = s; \
      } \
    } else { \
      const int base = 16 + (pairIdx - 16)*11; \
      { const int r = ln;       const int bb = (r*373)>>12; const int t = r - bb*11; \
        g_partKL[(size_t)(base + t)*NBATCH + bg0 + bb] = rs0; } \
      { const int r = ln + 64;  const int bb = (r*373)>>12; const int t = r - bb*11; \
        g_partKL[(size_t)(base + t)*NBATCH + bg0 + bb] = rs1; } \
      if (ln < 48) { \
        const int r = ln + 128; const int bb = (r*373)>>12; const int t = r - bb*11; \
        g_partKL[(size_t)(base + t)*NBATCH + bg0 + bb] = rs2; } \
    } \
  } else { \
    const int j2 = pairIdx - 32; \
    float* stg2 = (float*)(smem + STG2_OFF) + wnp * 896; \
    const float db1v = db1[j2*16 + lo16]; \
    const float dw2v = dW2[j2*16 + lo16]; \
    _Pragma("unroll") \
    for (int mf = 0; mf < 11; ++mf) { \
      _Pragma("unroll") \
      for (int e = 0; e < 4; ++e) { \
        const int r = mf*16 + 4*hi4 + e; \
        stg[r*33 + lo16]      = accA[mf][e]; \
        stg[r*33 + 16 + lo16] = accB[mf][e]; \
      } } \
    asm volatile("s_waitcnt lgkmcnt(0)" ::: "memory"); \
    _Pragma("unroll 1") \
    for (int it = 0; it < 4; ++it) { \
      const int bb = hi4 + 4*it; \
      float pi[11], pj[11]; \
      _Pragma("unroll") \
      for (int t = 0; t < 11; ++t) { \
        pi[t] = stg[(bb*11 + t)*33 + lo16] + db1v; \
        pj[t] = stg[(bb*11 + t)*33 + 16 + lo16]; \
      } \
      { /* pass 0: p 0..27 */ \
        float aP[28]; \
        _Pragma("unroll") \
        for (int p = 0; p < 28; ++p) \
          aP[p] = fmaxf(pi[II_[p]] + pj[JJ_[p]], 0.f) * dw2v; \
        _Pragma("unroll") \
        for (int p = 0; p < 28; ++p) { \
          aP[p] += __shfl_xor(aP[p], 1); \
          aP[p] += __shfl_xor(aP[p], 2); \
          aP[p] += __shfl_xor(aP[p], 4); \
          aP[p] += __shfl_xor(aP[p], 8); \
        } \
        _Pragma("unroll") \
        for (int p = 0; p < 28; ++p) \
          if (lo16 == (p & 15)) stg2[bb*56 + p] = aP[p]; \
      } \
      { /* pass 1: p 28..54 */ \
        float aP[27]; \
        _Pragma("unroll") \
        for (int p = 0; p < 27; ++p) \
          aP[p] = fmaxf(pi[II_[p+28]] + pj[JJ_[p+28]], 0.f) * dw2v; \
        _Pragma("unroll") \
        for (int p = 0; p < 27; ++p) { \
          aP[p] += __shfl_xor(aP[p], 1); \
          aP[p] += __shfl_xor(aP[p], 2); \
          aP[p] += __shfl_xor(aP[p], 4); \
          aP[p] += __shfl_xor(aP[p], 8); \
        } \
        _Pragma("unroll") \
        for (int p = 0; p < 27; ++p) \
          if (lo16 == ((p+28) & 15)) stg2[bb*56 + (p+28)] = aP[p]; \
      } \
    } \
    asm volatile("s_waitcnt lgkmcnt(0)" ::: "memory"); \
    { /* coalesced copy stg2 -> g_partI[j2][bg0..bg0+15][56] */ \
      float* gdst = g_partI + ((size_t)j2*NBATCH + bg0) * 56; \
      _Pragma("unroll") \
      for (int i = 0; i < 14; ++i) gdst[ln + 64*i] = stg2[ln + 64*i]; \
    } \
  } \
} while(0)

__launch_bounds__(512, 1)
__global__ void energy_mfma(
    const float* __restrict__ kb1, const float* __restrict__ kW2,
    const float* __restrict__ lb1, const float* __restrict__ lW2,
    const float* __restrict__ db1, const float* __restrict__ dW2)
{
    extern __shared__ char smem[];
    const int tid  = threadIdx.x;
    const int wv   = tid >> 6, ln = tid & 63;
    const int lo16 = ln & 15, hi4 = ln >> 4;
    const int wm   = wv >> 2, wnp = wv & 3;        // 2M x 4PAIR waves
    const int bx   = blockIdx.x;
    const int n    = bx >> 6;                      // 0..23
    const int m    = bx & 63;                      // 0..63
    const int pairIdx = n*4 + wnp;
    const int bg0  = m*32 + wm*16;

    f32x4 accA[11], accB[11];
    #pragma unroll
    for (int mf = 0; mf < 11; ++mf) {
        accA[mf] = (f32x4){0.f,0.f,0.f,0.f};
        accB[mf] = (f32x4){0.f,0.f,0.f,0.f};
    }

    // quad-buffer prologue: 3 steps in flight
    STAGE(0, 0*BUFSZ);
    STAGE(1, 1*BUFSZ);
    STAGE(2, 2*BUFSZ);

    #pragma unroll 1
    for (int step = 0; step < 29; ++step) {
        const int nb = (step + 3) & 3;
        STAGE(step + 3, nb*BUFSZ);
        asm volatile("s_waitcnt vmcnt(12)" ::: "memory");  // step's 4 loads done
        __builtin_amdgcn_s_barrier();
        MFMA_PHASE((step & 3)*BUFSZ);
        asm volatile("" ::: "memory");
        __builtin_amdgcn_s_barrier();
    }
    // peeled steps 29..31 (no more staging; drain progressively)
    asm volatile("s_waitcnt vmcnt(8)" ::: "memory");
    __builtin_amdgcn_s_barrier();
    MFMA_PHASE((29 & 3)*BUFSZ);
    asm volatile("" ::: "memory");
    __builtin_amdgcn_s_barrier();
    asm volatile("s_waitcnt vmcnt(4)" ::: "memory");
    __builtin_amdgcn_s_barrier();
    MFMA_PHASE((30 & 3)*BUFSZ);
    asm volatile("" ::: "memory");
    __builtin_amdgcn_s_barrier();
    asm volatile("s_waitcnt vmcnt(0)" ::: "memory");
    __builtin_amdgcn_s_barrier();
    MFMA_PHASE((31 & 3)*BUFSZ);
    asm volatile("" ::: "memory");
    __builtin_amdgcn_s_barrier();

    // epilogue: 2 rounds (wm); LDS regions per wnp (alias dead staging buffers)
    if (wm == 0) { EPILOGUE(); }
    __syncthreads();
    if (wm == 1) { EPILOGUE(); }
}

__global__ void finalize(
    const float* __restrict__ base_conf,
    const float* __restrict__ kb2, const float* __restrict__ lb2,
    const float* __restrict__ db2,
    const float* __restrict__ kwp, const float* __restrict__ lwp,
    const float* __restrict__ iwp, const float* __restrict__ tmpp,
    float* __restrict__ out)
{
    const int wv = threadIdx.x >> 6, ln = threadIdx.x & 63;
    const int b0 = (blockIdx.x*4 + wv)*4;          // 4 batches per wave
    const float kw = kwp[0], lw = lwp[0], iw = iwp[0], temp = tmpp[0];
    const float kb2v = kb2[0], lb2v = lb2[0], db2v = db2[0];

    #pragma unroll 1
    for (int bi = 0; bi < 4; ++bi) {
        const int b = b0 + bi;

        // ---- interaction: lane = j2, coalesced 16B chunks, full-wave reduce ----
        float is = 0.f;
        const float* ibase = g_partI + ((size_t)ln*NBATCH + b)*56;
        #pragma unroll
        for (int c = 0; c < 14; ++c) {
            f32x4 v = *(const f32x4*)(ibase + c*4);
            #pragma unroll
            for (int msk = 1; msk <= 32; msk <<= 1) {
                v[0] += __shfl_xor(v[0], msk);
                v[1] += __shfl_xor(v[1], msk);
                v[2] += __shfl_xor(v[2], msk);
                v[3] += __shfl_xor(v[3], msk);
            }
            #pragma unroll
            for (int k = 0; k < 4; ++k) {
                const int p = c*4 + k;
                if (p < 55)
                    is += fmaxf(v[k] + db2v, 0.f) *
                          (1.f / (float)(JJ_[p] - II_[p] + 1));
            }
        }

        // ---- kinetic: slots 0..15 ----
        float kv = (ln < 16) ? g_partKL[(size_t)ln*NBATCH + b] : 0.f;
        #pragma unroll
        for (int msk = 1; msk <= 32; msk <<= 1) kv += __shfl_xor(kv, msk);
        const float kinetic = -kw * (kv * (1.f/11.f) + kb2v);

        // ---- local: lane t<11 sums 16 j's, then gather ----
        float lv = 0.f;
        if (ln < 11) {
            #pragma unroll
            for (int j = 0; j < 16; ++j)
                lv += g_partKL[(size_t)(16 + j*11 + ln)*NBATCH + b];
        }
        float ls = 0.f;
        #pragma unroll
        for (int t = 0; t < 11; ++t)
            ls += fmaxf(__shfl(lv, t) + lb2v, 0.f);
        const float local_e = lw * (ls * (1.f/11.f));

        const float inter = iw * (is * (1.f/55.f));
        const float total = kinetic + local_e + inter;
        const float ec = 1.f / (1.f + expf(total / (fabsf(temp) + 0.1f)));
        if (ln == 0) {
            out[0*NBATCH + b] = total;
            out[1*NBATCH + b] = kinetic;
            out[2*NBATCH + b] = local_e;
            out[3*NBATCH + b] = inter;
            out[4*NBATCH + b] = ec;
            out[5*NBATCH + b] = base_conf[b] * ec;
        }
    }
}

extern "C" void kernel_launch(void* const* d_in, const int* in_sizes, int n_in,
                              void* d_out, int out_size, void* d_ws, size_t ws_size,
                              hipStream_t stream) {
    const float* h_stack   = (const float*)d_in[0];
    const float* base_conf = (const float*)d_in[1];
    const float* kW1 = (const float*)d_in[2];
    const float* kb1 = (const float*)d_in[3];
    const float* kW2 = (const float*)d_in[4];
    const float* kb2 = (const float*)d_in[5];
    const float* lW1 = (const float*)d_in[6];
    const float* lb1 = (const float*)d_in[7];
    const float* lW2 = (const float*)d_in[8];
    const float* lb2 = (const float*)d_in[9];
    const float* dW1 = (const float*)d_in[10];
    const float* db1 = (const float*)d_in[11];
    const float* dW2 = (const float*)d_in[12];
    const float* db2 = (const float*)d_in[13];
    const float* kwp = (const float*)d_in[14];
    const float* lwp = (const float*)d_in[15];
    const float* iwp = (const float*)d_in[16];
    const float* tmpp= (const float*)d_in[17];
    float* out = (float*)d_out;

    hipLaunchKernelGGL(pack_A, dim3(11264), dim3(256), 0, stream, h_stack);
    hipLaunchKernelGGL(pack_weights, dim3(1536), dim3(256), 0, stream, kW1, lW1, dW1);

    hipFuncSetAttribute((const void*)energy_mfma,
                        hipFuncAttributeMaxDynamicSharedMemorySize, LDS_TOTAL);
    hipLaunchKernelGGL(energy_mfma, dim3(NBLOCKS), dim3(512), LDS_TOTAL, stream,
                       kb1, kW2, lb1, lW2, db1, dW2);

    hipLaunchKernelGGL(finalize, dim3(128), dim3(256), 0, stream,
                       base_conf, kb2, lb2, db2, kwp, lwp, iwp, tmpp, out);
}